// Round 1
// baseline (18271.030 us; speedup 1.0000x reference)
//
#include <hip/hip_runtime.h>

#define TT  1024
#define BB  64
#define DIN 256
#define HH  512

// One launch per time step. Grid: (32 col-tiles of 16 h-cols, 8 batch-tiles of 8 rows).
// Block: 256 threads = (hc:16) x (r:8) x (half:2); tid = hc + 16*r + 128*half.
// Each block owns h-cols [col0,col0+16) across ALL 4 gates (z-cols col+{0,512,1024,1536}),
// so gates + c/h update fuse into the GEMM kernel. half=0 computes gates {f,i},
// half=1 computes {g,o}; combined via small LDS exchange.
__global__ __launch_bounds__(256)
void lstm_step(const float* __restrict__ x,       // [64,256]  x_t
               const float* __restrict__ h_prev,  // [64,512]  h_{t-1} (zeros buf for t=0)
               const float* __restrict__ W4,      // [768,2048]
               const float* __restrict__ b4,      // [2048]
               float* __restrict__ c_state,       // [64,512]  persistent c
               float* __restrict__ h_out)         // [64,512]  = stacked[t]
{
    // +4 pad on rows: stride 260 words -> bank = (4*row + k) & 31 -> worst 2-way (free)
    __shared__ float sW[64][260];   // W^T slice: [zcol_local][k_chunk]
    __shared__ float sC[8][260];    // combined [row][k_chunk]
    __shared__ float sZ[8][16][4];  // z exchange between halves

    const int tid  = threadIdx.x;
    const int hc   = tid & 15;         // h-col within tile
    const int r    = (tid >> 4) & 7;   // batch row within tile
    const int half = tid >> 7;         // 0: gates f,i   1: gates g,o
    const int col0 = blockIdx.x * 16;
    const int r0   = blockIdx.y * 8;

    float acc0 = 0.f, acc1 = 0.f;

    for (int ck = 0; ck < 3; ++ck) {
        const int k0 = ck << 8;        // K chunk base: 0 = x part, 256/512 = h part

        // ---- stage combined slice [8 rows x 256 k] (coalesced float4) ----
        const float* src;
        int stride;
        if (ck == 0) { src = x + r0 * DIN;                    stride = DIN; }
        else         { src = h_prev + r0 * HH + (k0 - 256);   stride = HH;  }
        for (int i = tid; i < 512; i += 256) {               // 512 float4
            int rr = i >> 6, kq = i & 63;
            float4 v = *(const float4*)(src + rr * stride + (kq << 2));
            *(float4*)&sC[rr][kq << 2] = v;
        }

        // ---- stage W^T slice [64 zcols x 256 k] (transpose in LDS) ----
        for (int i = tid; i < 4096; i += 256) {              // 4096 float4
            int kk = i >> 4, f4 = i & 15;
            int g = f4 >> 2, q = f4 & 3;
            float4 v = *(const float4*)(W4 + (size_t)(k0 + kk) * 2048
                                        + g * 512 + col0 + (q << 2));
            int cl = g * 16 + (q << 2);
            sW[cl + 0][kk] = v.x;
            sW[cl + 1][kk] = v.y;
            sW[cl + 2][kk] = v.z;
            sW[cl + 3][kk] = v.w;
        }
        __syncthreads();

        const int c0row = (half * 2 + 0) * 16 + hc;
        const int c1row = (half * 2 + 1) * 16 + hc;
        #pragma unroll 8
        for (int kk = 0; kk < 256; kk += 4) {
            float4 cv = *(const float4*)&sC[r][kk];
            float4 w0 = *(const float4*)&sW[c0row][kk];
            float4 w1 = *(const float4*)&sW[c1row][kk];
            acc0 += cv.x * w0.x; acc0 += cv.y * w0.y;
            acc0 += cv.z * w0.z; acc0 += cv.w * w0.w;
            acc1 += cv.x * w1.x; acc1 += cv.y * w1.y;
            acc1 += cv.z * w1.z; acc1 += cv.w * w1.w;
        }
        __syncthreads();
    }

    sZ[r][hc][half * 2 + 0] = acc0;
    sZ[r][hc][half * 2 + 1] = acc1;
    __syncthreads();

    if (half == 0) {
        const int col = col0 + hc;
        const int row = r0 + r;
        float zf = sZ[r][hc][0] + b4[col];
        float zi = sZ[r][hc][1] + b4[512 + col];
        float zg = sZ[r][hc][2] + b4[1024 + col];
        float zo = sZ[r][hc][3] + b4[1536 + col];
        float f = 1.f / (1.f + expf(-zf));
        float i = 1.f / (1.f + expf(-zi));
        float g = tanhf(zg);
        float o = 1.f / (1.f + expf(-zo));
        float cprev = c_state[row * HH + col];
        float cn = f * cprev + i * g;
        c_state[row * HH + col] = cn;
        h_out[row * HH + col] = o * tanhf(cn);
    }
}

extern "C" void kernel_launch(void* const* d_in, const int* in_sizes, int n_in,
                              void* d_out, int out_size, void* d_ws, size_t ws_size,
                              hipStream_t stream) {
    const float* x_all = (const float*)d_in[0];   // [1024,64,256]
    const float* W4    = (const float*)d_in[1];   // [768,2048]
    const float* b4    = (const float*)d_in[2];   // [2048]
    float* out = (float*)d_out;                   // stacked[1024,64,512] + hx + cx

    float* c_state = (float*)d_ws;                // 64*512 floats
    float* zeros   = c_state + BB * HH;           // 64*512 floats, h_{-1} = 0

    // ws is re-poisoned 0xAA before every timed call: zero c and the h0 buffer.
    hipMemsetAsync(d_ws, 0, (size_t)2 * BB * HH * sizeof(float), stream);

    dim3 grid(32, 8), block(256);
    for (int t = 0; t < TT; ++t) {
        const float* xt = x_all + (size_t)t * BB * DIN;
        const float* hp = (t == 0) ? zeros : out + (size_t)(t - 1) * BB * HH;
        lstm_step<<<grid, block, 0, stream>>>(xt, hp, W4, b4, c_state,
                                              out + (size_t)t * BB * HH);
    }

    // hx = stacked[T-1], cx = final c
    hipMemcpyAsync(out + (size_t)TT * BB * HH,
                   out + (size_t)(TT - 1) * BB * HH,
                   (size_t)BB * HH * sizeof(float), hipMemcpyDeviceToDevice, stream);
    hipMemcpyAsync(out + (size_t)TT * BB * HH + BB * HH,
                   c_state,
                   (size_t)BB * HH * sizeof(float), hipMemcpyDeviceToDevice, stream);
}